// Round 5
// baseline (326.350 us; speedup 1.0000x reference)
//
#include <hip/hip_runtime.h>
#include <stdint.h>

#define NODE_NUM 8192
#define NN 8384        // total nodes per graph (8384 = 131*64)
#define CC 128         // channels
#define BB 2           // batch
#define EE 262144      // edges per graph (2^18)

// ---- in-degree count per (batch,node); intra = same-type, inter = cross ----
__global__ void k_count(const int* __restrict__ ei,
                        int* __restrict__ deg_intra, int* __restrict__ deg_inter) {
  int g = blockIdx.x * blockDim.x + threadIdx.x;
  int b = g >> 18;
  int e = g & (EE - 1);
  const int* eb = ei + b * 2 * EE;
  int src = eb[e];
  int dst = eb[EE + e];
  if ((unsigned)src >= NN || (unsigned)dst >= NN) return;  // ws-corruption guard
  bool ss = (src < NODE_NUM) && (dst < NODE_NUM);
  bool tt = (src >= NODE_NUM) && (dst >= NODE_NUM);
  if (ss || tt) atomicAdd(&deg_intra[b * NN + dst], 1);
  else          atomicAdd(&deg_inter[b * NN + dst], 1);
}

// ---- exclusive scan -> rowptr; 1 wave per (batch,kind), shfl inclusive scan ----
__global__ void k_scan(const int* __restrict__ deg_intra, const int* __restrict__ deg_inter,
                       int* __restrict__ rp_intra, int* __restrict__ rp_inter) {
  int w = threadIdx.x >> 6;          // 0..3
  int lane = threadIdx.x & 63;
  int b = w >> 1, kind = w & 1;
  const int* deg = (kind ? deg_inter : deg_intra) + b * NN;
  int* rp = (kind ? rp_inter : rp_intra) + b * (NN + 1);
  int carry = 0;
  for (int base = 0; base < NN; base += 64) {
    int i = base + lane;
    int v = (i < NN) ? deg[i] : 0;
    int s = v;
#pragma unroll
    for (int o = 1; o < 64; o <<= 1) {
      int t = __shfl_up(s, o, 64);
      if (lane >= o) s += t;
    }
    if (i < NN) rp[i] = carry + s - v;   // exclusive prefix
    carry += __shfl(s, 63, 64);
  }
  if (lane == 0) rp[NN] = carry;
}

// ---- normalization factors ----
__global__ void k_norms(const int* __restrict__ deg_intra, const int* __restrict__ deg_inter,
                        float* __restrict__ dinv_intra, float* __restrict__ selfnorm,
                        float* __restrict__ dinv_inter) {
  int i = blockIdx.x * blockDim.x + threadIdx.x;
  if (i >= BB * NN) return;
  float df = (float)(deg_intra[i] + 1);   // gcn_norm adds a self loop
  dinv_intra[i] = rsqrtf(df);
  selfnorm[i] = 1.0f / df;
  int di = deg_inter[i];
  dinv_inter[i] = (di > 0) ? (1.0f / (float)di) : 0.0f;
}

// ---- CSR fill: slot = rowptr[dst] + atomic cursor; src-only column array ----
__global__ void k_fill(const int* __restrict__ ei,
                       const int* __restrict__ rp_intra, const int* __restrict__ rp_inter,
                       int* __restrict__ fill_intra, int* __restrict__ fill_inter,
                       int* __restrict__ colS_intra, int* __restrict__ colS_inter) {
  int g = blockIdx.x * blockDim.x + threadIdx.x;
  int b = g >> 18;
  int e = g & (EE - 1);
  const int* eb = ei + b * 2 * EE;
  int src = eb[e];
  int dst = eb[EE + e];
  if ((unsigned)src >= NN || (unsigned)dst >= NN) return;  // ws-corruption guard
  bool ss = (src < NODE_NUM) && (dst < NODE_NUM);
  bool tt = (src >= NODE_NUM) && (dst >= NODE_NUM);
  if (ss || tt) {
    int pos = atomicAdd(&fill_intra[b * NN + dst], 1);
    colS_intra[b * EE + rp_intra[b * (NN + 1) + dst] + pos] = src;
  } else {
    int pos = atomicAdd(&fill_inter[b * NN + dst], 1);
    colS_inter[b * EE + rp_inter[b * (NN + 1) + dst] + pos] = src;
  }
}

// ---- per-node projections: pi = h·W(type)[:C], pj = h·W(type)[C:]; 1 wave/node ----
__global__ void k_proj(const float* __restrict__ h,
                       const float* __restrict__ Wi_s, const float* __restrict__ Wj_s,
                       const float* __restrict__ Wi_t, const float* __restrict__ Wj_t,
                       float* __restrict__ pi, float* __restrict__ pj) {
  int wid = (blockIdx.x * blockDim.x + threadIdx.x) >> 6;  // global node id b*NN+n
  int lane = threadIdx.x & 63;
  int n = wid % NN;
  bool is_s = (n < NODE_NUM);
  const float* wi = is_s ? Wi_s : Wi_t;
  const float* wj = is_s ? Wj_s : Wj_t;
  float2 hv = *(const float2*)(h + (size_t)wid * CC + lane * 2);
  float2 wiv = *(const float2*)(wi + lane * 2);
  float2 wjv = *(const float2*)(wj + lane * 2);
  float a = hv.x * wiv.x + hv.y * wiv.y;
  float c = hv.x * wjv.x + hv.y * wjv.y;
#pragma unroll
  for (int o = 32; o > 0; o >>= 1) {
    a += __shfl_xor(a, o, 64);
    c += __shfl_xor(c, o, 64);
  }
  if (lane == 0) { pi[wid] = a; pj[wid] = c; }
}

// ---- gather with fused edge coefficients ----
// 1 wave per dst node; edges consumed in 64-wide chunks: each lane computes one
// edge's coef (tanh + norms), then the wave broadcasts (src,coef) via shfl and
// accumulates h[src] * coef with 2 channels/lane in registers. fp32 in/out.
template <bool INTRA, bool RELU>
__global__ void k_gather(const float* __restrict__ h_in, float* __restrict__ h_out,
                         const int* __restrict__ rp, const int* __restrict__ colS,
                         const float* __restrict__ pi, const float* __restrict__ pj,
                         const float* __restrict__ normD, const float* __restrict__ normS,
                         const float* __restrict__ selfnorm) {
  int wid = (blockIdx.x * blockDim.x + threadIdx.x) >> 6;
  int lane = threadIdx.x & 63;
  int b = wid / NN;
  int n = wid - b * NN;
  const int* rpb = rp + b * (NN + 1);
  int s0 = rpb[n], s1 = rpb[n + 1];
  const float* hb = h_in + (size_t)b * NN * CC;
  const float* pjb = pj + b * NN;
  const float* nsb = normS + b * NN;
  float p_i = pi[wid];
  float nd = normD[wid];
  const float2 hv = *(const float2*)(hb + (size_t)n * CC + lane * 2);
  float2 acc;
  if (INTRA) {
    // residual + self-loop message: h * (1 + tanh(pi+pj)/deg)
    float fac = 1.0f + tanhf(p_i + pjb[n]) * selfnorm[wid];
    acc.x = hv.x * fac;
    acc.y = hv.y * fac;
  } else {
    acc = hv;  // residual only
  }
  const int* cS = colS + (size_t)b * EE;
  for (int chunk = s0; chunk < s1; chunk += 64) {
    int rem = s1 - chunk;
    int m = rem < 64 ? rem : 64;
    int src = 0;
    float c = 0.0f;
    if (lane < m) {
      src = cS[chunk + lane];
      float a = tanhf(p_i + pjb[src]);
      c = a * nd;
      if (INTRA) c *= nsb[src];
    }
    for (int j = 0; j < m; ++j) {
      int sj = __shfl(src, j, 64);
      float cj = __shfl(c, j, 64);
      const float2 v = *(const float2*)(hb + (size_t)sj * CC + lane * 2);
      acc.x = fmaf(v.x, cj, acc.x);
      acc.y = fmaf(v.y, cj, acc.y);
    }
  }
  if (RELU) { acc.x = fmaxf(acc.x, 0.0f); acc.y = fmaxf(acc.y, 0.0f); }
  *(float2*)(h_out + (size_t)wid * CC + lane * 2) = acc;
}

extern "C" void kernel_launch(void* const* d_in, const int* in_sizes, int n_in,
                              void* d_out, int out_size, void* d_ws, size_t ws_size,
                              hipStream_t stream) {
  const float* x = (const float*)d_in[0];      // fp32 features [B,N,C]
  const int* ei = (const int*)d_in[1];         // int32 [B,2,E] (proven by R3==R4)
  const float* Wss = (const float*)d_in[2];    // fp32 [2, 2C]
  const float* Wtt = (const float*)d_in[3];
  const float* Wst = (const float*)d_in[4];
  const float* Wts = (const float*)d_in[5];
  float* out = (float*)d_out;                  // fp32 output [B,N,C]

  char* p = (char*)d_ws;
  auto alloc = [&](size_t bytes) {
    void* r = (void*)p;
    p += ((bytes + 255) & ~(size_t)255);
    return r;
  };
  float* h0 = (float*)alloc((size_t)BB * NN * CC * 4);
  float* h1 = (float*)alloc((size_t)BB * NN * CC * 4);
  float* pi = (float*)alloc(BB * NN * 4);
  float* pj = (float*)alloc(BB * NN * 4);
  float* dinv_intra = (float*)alloc(BB * NN * 4);
  float* selfnorm = (float*)alloc(BB * NN * 4);
  float* dinv_inter = (float*)alloc(BB * NN * 4);
  int* deg_intra = (int*)alloc(BB * NN * 4);   // deg_intra..fill_inter contiguous
  int* deg_inter = (int*)alloc(BB * NN * 4);   // (67072 % 256 == 0) -> one memset
  int* fill_intra = (int*)alloc(BB * NN * 4);  // zeroes all four.
  int* fill_inter = (int*)alloc(BB * NN * 4);
  int* rp_intra = (int*)alloc(BB * (NN + 1) * 4);
  int* rp_inter = (int*)alloc(BB * (NN + 1) * 4);
  int* colS_intra = (int*)alloc((size_t)BB * EE * 4);
  int* colS_inter = (int*)alloc((size_t)BB * EE * 4);
  // total ws use: ~21.1 MB

  hipMemsetAsync(deg_intra, 0, (size_t)4 * BB * NN * 4, stream);

  k_count<<<(BB * EE) / 256, 256, 0, stream>>>(ei, deg_intra, deg_inter);
  k_scan<<<1, 256, 0, stream>>>(deg_intra, deg_inter, rp_intra, rp_inter);
  k_norms<<<(BB * NN + 255) / 256, 256, 0, stream>>>(deg_intra, deg_inter,
                                                     dinv_intra, selfnorm, dinv_inter);
  k_fill<<<(BB * EE) / 256, 256, 0, stream>>>(ei, rp_intra, rp_inter,
                                              fill_intra, fill_inter,
                                              colS_intra, colS_inter);

  const int NODE_BLOCKS = (BB * NN * 64) / 256;  // 1 wave per node, 4 waves/block
  const float* hc = x;    // layer-0 input straight from d_in
  float* hn = h0;
  float* spare = h1;
  for (int li = 0; li < 2; ++li) {
    const float* wss = Wss + li * 256;
    const float* wtt = Wtt + li * 256;
    const float* wst = Wst + li * 256;
    const float* wts = Wts + li * 256;

    // ---- intra layer (SSConv + TTConv), relu after ----
    k_proj<<<NODE_BLOCKS, 256, 0, stream>>>(hc, wss, wss + 128, wtt, wtt + 128, pi, pj);
    k_gather<true, true><<<NODE_BLOCKS, 256, 0, stream>>>(
        hc, hn, rp_intra, colS_intra, pi, pj, dinv_intra, dinv_intra, selfnorm);
    { const float* t = hc; hc = hn; hn = (li == 0 && t == x) ? spare : (float*)t; }

    // ---- inter layer (STConv + TSConv); relu only after li=0 ----
    // s-node: pi uses W_ts[:C] (dst of t->s), pj uses W_st[C:] (src of s->t)
    // t-node: pi uses W_st[:C] (dst of s->t), pj uses W_ts[C:] (src of t->s)
    k_proj<<<NODE_BLOCKS, 256, 0, stream>>>(hc, wts, wst + 128, wst, wts + 128, pi, pj);
    if (li == 0) {
      k_gather<false, true><<<NODE_BLOCKS, 256, 0, stream>>>(
          hc, hn, rp_inter, colS_inter, pi, pj, dinv_inter, dinv_inter, selfnorm);
      { const float* t = hc; hc = hn; hn = (float*)t; }
    } else {
      k_gather<false, false><<<NODE_BLOCKS, 256, 0, stream>>>(
          hc, out, rp_inter, colS_inter, pi, pj, dinv_inter, dinv_inter, selfnorm);
    }
  }
}

// Round 6
// 274.461 us; speedup vs baseline: 1.1891x; 1.1891x over previous
//
#include <hip/hip_runtime.h>
#include <stdint.h>

#define NODE_NUM 8192
#define NN 8384        // total nodes per graph (8384 = 131*64)
#define CC 128         // channels
#define BB 2           // batch
#define EE 262144      // edges per graph (2^18)

// ---- in-degree count per (batch,node); intra = same-type, inter = cross ----
__global__ void k_count(const int* __restrict__ ei,
                        int* __restrict__ deg_intra, int* __restrict__ deg_inter) {
  int g = blockIdx.x * blockDim.x + threadIdx.x;
  int b = g >> 18;
  int e = g & (EE - 1);
  const int* eb = ei + b * 2 * EE;
  int src = eb[e];
  int dst = eb[EE + e];
  if ((unsigned)src >= NN || (unsigned)dst >= NN) return;  // ws-corruption guard
  bool ss = (src < NODE_NUM) && (dst < NODE_NUM);
  bool tt = (src >= NODE_NUM) && (dst >= NODE_NUM);
  if (ss || tt) atomicAdd(&deg_intra[b * NN + dst], 1);
  else          atomicAdd(&deg_inter[b * NN + dst], 1);
}

// ---- block-parallel exclusive scan -> rowptr, fused norm computation ----
// grid = 4 blocks (batch,kind), 1024 threads; 9 elems/thread; LDS scan of sums.
__global__ void k_scan(const int* __restrict__ deg_intra, const int* __restrict__ deg_inter,
                       int* __restrict__ rp_intra, int* __restrict__ rp_inter,
                       float* __restrict__ dinv_intra, float* __restrict__ selfnorm,
                       float* __restrict__ dinv_inter) {
  int b = blockIdx.x >> 1, kind = blockIdx.x & 1;
  const int* deg = (kind ? deg_inter : deg_intra) + b * NN;
  int* rp = (kind ? rp_inter : rp_intra) + b * (NN + 1);
  const int PER = 9;                    // 1024*9 = 9216 >= 8384
  int tid = threadIdx.x;
  int base = tid * PER;
  int v[PER];
  int sum = 0;
#pragma unroll
  for (int k = 0; k < PER; k++) {
    int i = base + k;
    v[k] = (i < NN) ? deg[i] : 0;
    sum += v[k];
  }
  __shared__ int sd[1024];
  sd[tid] = sum;
  __syncthreads();
  for (int ofs = 1; ofs < 1024; ofs <<= 1) {
    int t = (tid >= ofs) ? sd[tid - ofs] : 0;
    __syncthreads();
    sd[tid] += t;
    __syncthreads();
  }
  int excl = sd[tid] - sum;
#pragma unroll
  for (int k = 0; k < PER; k++) {
    int i = base + k;
    if (i < NN) rp[i] = excl;
    excl += v[k];
  }
  if (tid == 1023) rp[NN] = sd[1023];
  // fused normalization factors (deg already in registers)
#pragma unroll
  for (int k = 0; k < PER; k++) {
    int i = base + k;
    if (i >= NN) continue;
    if (kind == 0) {
      float df = (float)(v[k] + 1);     // gcn_norm adds a self loop
      dinv_intra[b * NN + i] = rsqrtf(df);
      selfnorm[b * NN + i] = 1.0f / df;
    } else {
      dinv_inter[b * NN + i] = (v[k] > 0) ? (1.0f / (float)v[k]) : 0.0f;
    }
  }
}

// ---- CSR fill: slot = rowptr[dst] + atomic cursor; src-only column array ----
__global__ void k_fill(const int* __restrict__ ei,
                       const int* __restrict__ rp_intra, const int* __restrict__ rp_inter,
                       int* __restrict__ fill_intra, int* __restrict__ fill_inter,
                       int* __restrict__ colS_intra, int* __restrict__ colS_inter) {
  int g = blockIdx.x * blockDim.x + threadIdx.x;
  int b = g >> 18;
  int e = g & (EE - 1);
  const int* eb = ei + b * 2 * EE;
  int src = eb[e];
  int dst = eb[EE + e];
  if ((unsigned)src >= NN || (unsigned)dst >= NN) return;  // ws-corruption guard
  bool ss = (src < NODE_NUM) && (dst < NODE_NUM);
  bool tt = (src >= NODE_NUM) && (dst >= NODE_NUM);
  if (ss || tt) {
    int pos = atomicAdd(&fill_intra[b * NN + dst], 1);
    colS_intra[b * EE + rp_intra[b * (NN + 1) + dst] + pos] = src;
  } else {
    int pos = atomicAdd(&fill_inter[b * NN + dst], 1);
    colS_inter[b * EE + rp_inter[b * (NN + 1) + dst] + pos] = src;
  }
}

// ---- per-node projections: pi = h·W(type)[:C], pj = h·W(type)[C:]; 1 wave/node ----
__global__ void k_proj(const float* __restrict__ h,
                       const float* __restrict__ Wi_s, const float* __restrict__ Wj_s,
                       const float* __restrict__ Wi_t, const float* __restrict__ Wj_t,
                       float* __restrict__ pi, float* __restrict__ pj) {
  int wid = (blockIdx.x * blockDim.x + threadIdx.x) >> 6;  // global node id b*NN+n
  int lane = threadIdx.x & 63;
  int n = wid % NN;
  bool is_s = (n < NODE_NUM);
  const float* wi = is_s ? Wi_s : Wi_t;
  const float* wj = is_s ? Wj_s : Wj_t;
  float2 hv = *(const float2*)(h + (size_t)wid * CC + lane * 2);
  float2 wiv = *(const float2*)(wi + lane * 2);
  float2 wjv = *(const float2*)(wj + lane * 2);
  float a = hv.x * wiv.x + hv.y * wiv.y;
  float c = hv.x * wjv.x + hv.y * wjv.y;
#pragma unroll
  for (int o = 32; o > 0; o >>= 1) {
    a += __shfl_xor(a, o, 64);
    c += __shfl_xor(c, o, 64);
  }
  if (lane == 0) { pi[wid] = a; pj[wid] = c; }
}

// ---- gather with fused edge coefficients ----
// 1 wave per dst node; edges consumed in 64-wide chunks: each lane computes one
// edge's coef (tanh + norms), then the wave broadcasts (src,coef) via shfl and
// accumulates h[src] * coef with 2 channels/lane in registers. fp32 in/out.
template <bool INTRA, bool RELU>
__global__ void k_gather(const float* __restrict__ h_in, float* __restrict__ h_out,
                         const int* __restrict__ rp, const int* __restrict__ colS,
                         const float* __restrict__ pi, const float* __restrict__ pj,
                         const float* __restrict__ normD, const float* __restrict__ normS,
                         const float* __restrict__ selfnorm) {
  int wid = (blockIdx.x * blockDim.x + threadIdx.x) >> 6;
  int lane = threadIdx.x & 63;
  int b = wid / NN;
  int n = wid - b * NN;
  const int* rpb = rp + b * (NN + 1);
  int s0 = rpb[n], s1 = rpb[n + 1];
  const float* hb = h_in + (size_t)b * NN * CC;
  const float* pjb = pj + b * NN;
  const float* nsb = normS + b * NN;
  float p_i = pi[wid];
  float nd = normD[wid];
  const float2 hv = *(const float2*)(hb + (size_t)n * CC + lane * 2);
  float2 acc;
  if (INTRA) {
    // residual + self-loop message: h * (1 + tanh(pi+pj)/deg)
    float fac = 1.0f + tanhf(p_i + pjb[n]) * selfnorm[wid];
    acc.x = hv.x * fac;
    acc.y = hv.y * fac;
  } else {
    acc = hv;  // residual only
  }
  const int* cS = colS + (size_t)b * EE;
  for (int chunk = s0; chunk < s1; chunk += 64) {
    int rem = s1 - chunk;
    int m = rem < 64 ? rem : 64;
    int src = 0;
    float c = 0.0f;
    if (lane < m) {
      src = cS[chunk + lane];
      float a = tanhf(p_i + pjb[src]);
      c = a * nd;
      if (INTRA) c *= nsb[src];
    }
    for (int j = 0; j < m; ++j) {
      int sj = __shfl(src, j, 64);
      float cj = __shfl(c, j, 64);
      const float2 v = *(const float2*)(hb + (size_t)sj * CC + lane * 2);
      acc.x = fmaf(v.x, cj, acc.x);
      acc.y = fmaf(v.y, cj, acc.y);
    }
  }
  if (RELU) { acc.x = fmaxf(acc.x, 0.0f); acc.y = fmaxf(acc.y, 0.0f); }
  *(float2*)(h_out + (size_t)wid * CC + lane * 2) = acc;
}

extern "C" void kernel_launch(void* const* d_in, const int* in_sizes, int n_in,
                              void* d_out, int out_size, void* d_ws, size_t ws_size,
                              hipStream_t stream) {
  const float* x = (const float*)d_in[0];      // fp32 features [B,N,C]
  const int* ei = (const int*)d_in[1];         // int32 [B,2,E]
  const float* Wss = (const float*)d_in[2];    // fp32 [2, 2C]
  const float* Wtt = (const float*)d_in[3];
  const float* Wst = (const float*)d_in[4];
  const float* Wts = (const float*)d_in[5];
  float* out = (float*)d_out;                  // fp32 output [B,N,C]

  char* p = (char*)d_ws;
  auto alloc = [&](size_t bytes) {
    void* r = (void*)p;
    p += ((bytes + 255) & ~(size_t)255);
    return r;
  };
  float* h0 = (float*)alloc((size_t)BB * NN * CC * 4);
  float* h1 = (float*)alloc((size_t)BB * NN * CC * 4);
  float* pi = (float*)alloc(BB * NN * 4);
  float* pj = (float*)alloc(BB * NN * 4);
  float* dinv_intra = (float*)alloc(BB * NN * 4);
  float* selfnorm = (float*)alloc(BB * NN * 4);
  float* dinv_inter = (float*)alloc(BB * NN * 4);
  int* deg_intra = (int*)alloc(BB * NN * 4);   // deg_intra..fill_inter contiguous
  int* deg_inter = (int*)alloc(BB * NN * 4);   // (67072 % 256 == 0) -> one memset
  int* fill_intra = (int*)alloc(BB * NN * 4);  // zeroes all four.
  int* fill_inter = (int*)alloc(BB * NN * 4);
  int* rp_intra = (int*)alloc(BB * (NN + 1) * 4);
  int* rp_inter = (int*)alloc(BB * (NN + 1) * 4);
  int* colS_intra = (int*)alloc((size_t)BB * EE * 4);
  int* colS_inter = (int*)alloc((size_t)BB * EE * 4);
  // total ws use: ~21.1 MB

  hipMemsetAsync(deg_intra, 0, (size_t)4 * BB * NN * 4, stream);

  k_count<<<(BB * EE) / 256, 256, 0, stream>>>(ei, deg_intra, deg_inter);
  k_scan<<<4, 1024, 0, stream>>>(deg_intra, deg_inter, rp_intra, rp_inter,
                                 dinv_intra, selfnorm, dinv_inter);
  k_fill<<<(BB * EE) / 256, 256, 0, stream>>>(ei, rp_intra, rp_inter,
                                              fill_intra, fill_inter,
                                              colS_intra, colS_inter);

  const int NODE_BLOCKS = (BB * NN * 64) / 256;  // 1 wave per node, 4 waves/block
  const float* hc = x;    // layer-0 input straight from d_in
  float* hn = h0;
  float* spare = h1;
  for (int li = 0; li < 2; ++li) {
    const float* wss = Wss + li * 256;
    const float* wtt = Wtt + li * 256;
    const float* wst = Wst + li * 256;
    const float* wts = Wts + li * 256;

    // ---- intra layer (SSConv + TTConv), relu after ----
    k_proj<<<NODE_BLOCKS, 256, 0, stream>>>(hc, wss, wss + 128, wtt, wtt + 128, pi, pj);
    k_gather<true, true><<<NODE_BLOCKS, 256, 0, stream>>>(
        hc, hn, rp_intra, colS_intra, pi, pj, dinv_intra, dinv_intra, selfnorm);
    { const float* t = hc; hc = hn; hn = (li == 0 && t == x) ? spare : (float*)t; }

    // ---- inter layer (STConv + TSConv); relu only after li=0 ----
    // s-node: pi uses W_ts[:C] (dst of t->s), pj uses W_st[C:] (src of s->t)
    // t-node: pi uses W_st[:C] (dst of s->t), pj uses W_ts[C:] (src of t->s)
    k_proj<<<NODE_BLOCKS, 256, 0, stream>>>(hc, wts, wst + 128, wst, wts + 128, pi, pj);
    if (li == 0) {
      k_gather<false, true><<<NODE_BLOCKS, 256, 0, stream>>>(
          hc, hn, rp_inter, colS_inter, pi, pj, dinv_inter, dinv_inter, selfnorm);
      { const float* t = hc; hc = hn; hn = (float*)t; }
    } else {
      k_gather<false, false><<<NODE_BLOCKS, 256, 0, stream>>>(
          hc, out, rp_inter, colS_inter, pi, pj, dinv_inter, dinv_inter, selfnorm);
    }
  }
}